// Round 11
// baseline (350.075 us; speedup 1.0000x reference)
//
#include <hip/hip_runtime.h>
#include <hip/hip_bf16.h>
#include <float.h>

#define N_NODES 30000
#define IN_CH   256
#define HID     128
#define HEADS   4
#define OUT_CH  256
#define N_EDGES 480000
#define TOT_E   (N_EDGES + N_NODES)

typedef unsigned short u16;   // bf16 bits
typedef __attribute__((ext_vector_type(8))) unsigned short u16x8;
typedef __attribute__((ext_vector_type(8))) short          s16x8;  // MFMA A/B frag (8 bf16)
typedef __attribute__((ext_vector_type(4))) float          f32x4;  // MFMA C/D frag

__device__ inline float bf2f(u16 u) {
    union { unsigned int i; float f; } v; v.i = ((unsigned int)u) << 16; return v.f;
}
__device__ inline u16 f2bf(float f) {
    union { float f; unsigned int i; } u; u.f = f;
    unsigned int r = u.i + 0x7FFF + ((u.i >> 16) & 1);
    return (u16)(r >> 16);
}

// ---------- dtype detection: bf16 exponent field vs fp32 mantissa bits -----
__global__ void detect_k(const unsigned int* __restrict__ w, int* __restrict__ flag) {
    __shared__ int votes;
    if (threadIdx.x == 0) votes = 0;
    __syncthreads();
    int v = 0;
    for (int i = threadIdx.x; i < 2048; i += 256) {
        unsigned int e = (w[i] >> 7) & 0xFFu;
        if (e >= 100u && e <= 140u) v++;
    }
    atomicAdd(&votes, v);
    __syncthreads();
    if (threadIdx.x == 0) *flag = (votes > 1024) ? 1 : 0;
}

// ---------- one-launch conversion + zero + vsd (block-range dispatch) -------
// blocks [0,512):     W1 [256][512] -> W1t [512][256] bf16
// blocks [512,1024):  W2 [512][256] -> W2t [256][512] bf16
// blocks [1024,1034): 7 small vectors -> fp32 (2305 elems)
// blocks [1034,1386): zero 90000 ints (als2v, ald2v, cnt)
// blocks [1386,1394): vsd[v][k] = sum_c bf16(W1[k, h*128+c]) * a[h][c]
//                     (v: 0-3 src heads, 4-7 dst heads; inline conversions
//                     are bit-exact with the previous W1t/as1f-based version)
__global__ void wconv_k(const void* __restrict__ W1, const void* __restrict__ W2,
                        const void* __restrict__ as1, const void* __restrict__ ad1,
                        const void* __restrict__ b1,  const void* __restrict__ as2,
                        const void* __restrict__ ad2, const void* __restrict__ b2,
                        const void* __restrict__ pw,
                        u16* __restrict__ W1t, u16* __restrict__ W2t,
                        float* __restrict__ as1f, float* __restrict__ ad1f,
                        float* __restrict__ b1f,  float* __restrict__ as2f,
                        float* __restrict__ ad2f, float* __restrict__ b2f,
                        float* __restrict__ pwf,
                        int* __restrict__ zeroreg,
                        float* __restrict__ vsd,
                        const int* __restrict__ flag)
{
    int b = blockIdx.x, t = threadIdx.x;
    int f = *flag;
    if (b < 512) {
        int idx = b*256 + t;                 // 0..131071
        int r = idx >> 9, c = idx & 511;     // W1 [256][512]
        u16 v = f ? ((const u16*)W1)[idx] : f2bf(((const float*)W1)[idx]);
        W1t[(size_t)c*256 + r] = v;
    } else if (b < 1024) {
        int idx = (b-512)*256 + t;           // 0..131071
        int r = idx >> 8, c = idx & 255;     // W2 [512][256]
        u16 v = f ? ((const u16*)W2)[idx] : f2bf(((const float*)W2)[idx]);
        W2t[(size_t)c*512 + r] = v;
    } else if (b < 1034) {
        int i = (b-1024)*256 + t;            // 0..2559
#define CV(in, k) (f ? bf2f(((const u16*)(in))[k]) : ((const float*)(in))[k])
        if      (i < 512)  as1f[i]        = CV(as1, i);
        else if (i < 1024) ad1f[i - 512]  = CV(ad1, i - 512);
        else if (i < 1536) b1f [i - 1024] = CV(b1,  i - 1024);
        else if (i < 1792) as2f[i - 1536] = CV(as2, i - 1536);
        else if (i < 2048) ad2f[i - 1792] = CV(ad2, i - 1792);
        else if (i < 2304) b2f [i - 2048] = CV(b2,  i - 2048);
        else if (i == 2304) pwf[0]        = CV(pw, 0);
    } else if (b < 1386) {
        int i = (b-1034)*256 + t;
        if (i < 90000) zeroreg[i] = 0;
    } else {
        int idx = (b-1386)*256 + t;          // 0..2047
        if (idx < 2048) {
            int v = idx >> 8;                // 0..7
            int k = idx & 255;
            int h = v & 3;
            const void* av = (v < 4) ? as1 : ad1;
            float s = 0.f;
            for (int c = 0; c < 128; ++c) {
                int wi = k*512 + h*128 + c;
                u16 w16 = f ? ((const u16*)W1)[wi] : f2bf(((const float*)W1)[wi]);
                s += bf2f(w16) * CV(av, h*128 + c);
            }
            vsd[idx] = s;
        }
#undef CV
    }
}

// ---------- fused x convert + layer-1 logits + CSR count --------------------
// blocks [0, 7500): 4 nodes per block (one wave each) — converts x -> xb and
//   computes als1/ald1 from POST-ROUNDING bf16 values (bit-exact parity).
// blocks [7500, 7500+1993): degree count (atomicAdd into cnt).
#define XPB 7500
__global__ __launch_bounds__(256) void xprep_k(
    const void* __restrict__ x, const float* __restrict__ vsd,
    u16* __restrict__ xb, float* __restrict__ als, float* __restrict__ ald,
    const int* __restrict__ ei, int* __restrict__ cnt,
    const int* __restrict__ flag)
{
    int b = blockIdx.x;
    if (b >= XPB) {
        int i = (b - XPB)*256 + threadIdx.x;
        if (i < TOT_E) {
            int d = (i < N_EDGES) ? ei[N_EDGES + i] : (i - N_EDGES);
            atomicAdd(&cnt[d], 1);
        }
        return;
    }
    int n = b * 4 + (threadIdx.x >> 6);
    int lane = threadIdx.x & 63;
    if (n >= N_NODES) return;
    int c0 = lane * 4;
    u16 xr[4];
    if (*flag) {
        ushort4 v = *(const ushort4*)((const u16*)x + (size_t)n*IN_CH + c0);
        xr[0]=v.x; xr[1]=v.y; xr[2]=v.z; xr[3]=v.w;
    } else {
        float4 v = *(const float4*)((const float*)x + (size_t)n*IN_CH + c0);
        xr[0]=f2bf(v.x); xr[1]=f2bf(v.y); xr[2]=f2bf(v.z); xr[3]=f2bf(v.w);
    }
    ushort4 o; o.x=xr[0]; o.y=xr[1]; o.z=xr[2]; o.w=xr[3];
    *(ushort4*)(xb + (size_t)n*IN_CH + c0) = o;
    float x0=bf2f(xr[0]), x1=bf2f(xr[1]), x2=bf2f(xr[2]), x3=bf2f(xr[3]);
#pragma unroll
    for (int v = 0; v < 8; ++v) {
        float4 vv = *(const float4*)(vsd + v*256 + c0);
        float d = x0*vv.x + x1*vv.y + x2*vv.z + x3*vv.w;
#pragma unroll
        for (int o2 = 32; o2 > 0; o2 >>= 1) d += __shfl_xor(d, o2);
        if (lane == 0) {
            if (v < 4) als[(size_t)n*4 + v]     = d;
            else       ald[(size_t)n*4 + v - 4] = d;
        }
    }
}

// ---------------- MFMA GEMM + fused logits epilogue (layer 2) --------------
__global__ __launch_bounds__(256) void gemm_bf_k(const u16* __restrict__ A,
                                                 const u16* __restrict__ Bt,
                                                 u16* __restrict__ Cb,
                                                 const float* __restrict__ a_s,
                                                 const float* __restrict__ a_d,
                                                 float* __restrict__ als,
                                                 float* __restrict__ ald,
                                                 int M, int N, int K,
                                                 int H, int hshift)
{
    __shared__ __align__(16) u16 As[128][40];
    __shared__ __align__(16) u16 Bs[128][40];

    const int tid  = threadIdx.x;
    const int wid  = tid >> 6;
    const int lane = tid & 63;
    const int wr   = wid >> 1;
    const int wc   = wid & 1;
    const int lr   = lane & 15;
    const int lg   = lane >> 4;
    const int row0 = blockIdx.y * 128;
    const int col0 = blockIdx.x * 128;

    const int st_r = tid >> 1;
    const int st_c = (tid & 1) << 4;

    f32x4 acc[4][4];
#pragma unroll
    for (int i = 0; i < 4; ++i)
#pragma unroll
        for (int j = 0; j < 4; ++j)
            acc[i][j] = (f32x4){0.f, 0.f, 0.f, 0.f};

    for (int k0 = 0; k0 < K; k0 += 32) {
        __syncthreads();
        {
            u16x8 a0 = {}, a1 = {};
            int ar = row0 + st_r;
            if (ar < M) {
                const u16* ap = A + (size_t)ar * K + k0 + st_c;
                a0 = *(const u16x8*)ap;
                a1 = *(const u16x8*)(ap + 8);
            }
            *(u16x8*)&As[st_r][st_c]     = a0;
            *(u16x8*)&As[st_r][st_c + 8] = a1;
            const u16* bp = Bt + (size_t)(col0 + st_r) * K + k0 + st_c;
            *(u16x8*)&Bs[st_r][st_c]     = *(const u16x8*)bp;
            *(u16x8*)&Bs[st_r][st_c + 8] = *(const u16x8*)(bp + 8);
        }
        __syncthreads();

        s16x8 af[4], bf[4];
#pragma unroll
        for (int mf = 0; mf < 4; ++mf)
            af[mf] = *(const s16x8*)&As[wr*64 + mf*16 + lr][lg*8];
#pragma unroll
        for (int nf = 0; nf < 4; ++nf)
            bf[nf] = *(const s16x8*)&Bs[wc*64 + nf*16 + lr][lg*8];
#pragma unroll
        for (int mf = 0; mf < 4; ++mf)
#pragma unroll
            for (int nf = 0; nf < 4; ++nf)
                acc[mf][nf] = __builtin_amdgcn_mfma_f32_16x16x32_bf16(
                    af[mf], bf[nf], acc[mf][nf], 0, 0, 0);
    }

    const int head = (col0 + wc*64) >> hshift;
    float asj[4], adj[4];
#pragma unroll
    for (int nf = 0; nf < 4; ++nf) {
        int j = col0 + wc*64 + nf*16 + lr;
        asj[nf] = a_s[j];
        adj[nf] = a_d[j];
    }
#pragma unroll
    for (int mf = 0; mf < 4; ++mf) {
#pragma unroll
        for (int r = 0; r < 4; ++r) {
            int rr = row0 + wr*64 + mf*16 + lg*4 + r;
            float ss = 0.f, sd = 0.f;
#pragma unroll
            for (int nf = 0; nf < 4; ++nf) {
                float v = acc[mf][nf][r];
                ss += v * asj[nf];
                sd += v * adj[nf];
            }
#pragma unroll
            for (int m2 = 1; m2 < 16; m2 <<= 1) {
                ss += __shfl_xor(ss, m2);
                sd += __shfl_xor(sd, m2);
            }
            if (rr < M) {
                if (lr == 0) {
                    atomicAdd(&als[(size_t)rr * H + head], ss);
                    atomicAdd(&ald[(size_t)rr * H + head], sd);
                }
                size_t base = (size_t)rr * N + col0 + wc*64 + lr;
#pragma unroll
                for (int nf = 0; nf < 4; ++nf)
                    Cb[base + nf*16] = f2bf(acc[mf][nf][r]);
            }
        }
    }
}

// ---------------- head-blocked MFMA GEMM (layer 1): h1p = aggx_h @ W1_h -----
__global__ __launch_bounds__(256) void gemm_h1_k(const u16* __restrict__ A,
                                                 const u16* __restrict__ Bt,
                                                 u16* __restrict__ Cb,
                                                 const float* __restrict__ bias,
                                                 const float* __restrict__ prelu_w,
                                                 int M)
{
    __shared__ __align__(16) u16 As[128][40];
    __shared__ __align__(16) u16 Bs[128][40];

    const int h    = blockIdx.z;
    const int tid  = threadIdx.x;
    const int wid  = tid >> 6;
    const int lane = tid & 63;
    const int wr   = wid >> 1;
    const int wc   = wid & 1;
    const int lr   = lane & 15;
    const int lg   = lane >> 4;
    const int row0 = blockIdx.y * 128;

    const int st_r = tid >> 1;
    const int st_c = (tid & 1) << 4;

    f32x4 acc[4][4];
#pragma unroll
    for (int i = 0; i < 4; ++i)
#pragma unroll
        for (int j = 0; j < 4; ++j)
            acc[i][j] = (f32x4){0.f, 0.f, 0.f, 0.f};

    for (int k0 = 0; k0 < 256; k0 += 32) {
        __syncthreads();
        {
            u16x8 a0 = {}, a1 = {};
            int ar = row0 + st_r;
            if (ar < M) {
                const u16* ap = A + (size_t)ar * 1024 + h*256 + k0 + st_c;
                a0 = *(const u16x8*)ap;
                a1 = *(const u16x8*)(ap + 8);
            }
            *(u16x8*)&As[st_r][st_c]     = a0;
            *(u16x8*)&As[st_r][st_c + 8] = a1;
            const u16* bp = Bt + (size_t)(h*128 + st_r) * 256 + k0 + st_c;
            *(u16x8*)&Bs[st_r][st_c]     = *(const u16x8*)bp;
            *(u16x8*)&Bs[st_r][st_c + 8] = *(const u16x8*)(bp + 8);
        }
        __syncthreads();

        s16x8 af[4], bf[4];
#pragma unroll
        for (int mf = 0; mf < 4; ++mf)
            af[mf] = *(const s16x8*)&As[wr*64 + mf*16 + lr][lg*8];
#pragma unroll
        for (int nf = 0; nf < 4; ++nf)
            bf[nf] = *(const s16x8*)&Bs[wc*64 + nf*16 + lr][lg*8];
#pragma unroll
        for (int mf = 0; mf < 4; ++mf)
#pragma unroll
            for (int nf = 0; nf < 4; ++nf)
                acc[mf][nf] = __builtin_amdgcn_mfma_f32_16x16x32_bf16(
                    af[mf], bf[nf], acc[mf][nf], 0, 0, 0);
    }

    const float pw = *prelu_w;
#pragma unroll
    for (int mf = 0; mf < 4; ++mf) {
#pragma unroll
        for (int r = 0; r < 4; ++r) {
            int rr = row0 + wr*64 + mf*16 + lg*4 + r;
            if (rr >= M) continue;
            size_t base = (size_t)rr * 512 + h*128 + wc*64 + lr;
#pragma unroll
            for (int nf = 0; nf < 4; ++nf) {
                int j = wc*64 + nf*16 + lr;
                float v = acc[mf][nf][r] + bias[h*128 + j];
                v = (v >= 0.f) ? v : pw * v;
                Cb[base + nf*16] = f2bf(v);
            }
        }
    }
}

// ---------------- CSR build (count lives in xprep_k) ------------------------
__global__ __launch_bounds__(1024) void scan1_k(const int* __restrict__ cnt,
                                                int* __restrict__ offs,
                                                int* __restrict__ btot)
{
    __shared__ int sm[1024];
    int tid = threadIdx.x;
    int i = blockIdx.x * 1024 + tid;
    int v = (i < N_NODES) ? cnt[i] : 0;
    sm[tid] = v;
    __syncthreads();
    for (int off = 1; off < 1024; off <<= 1) {
        int t = (tid >= off) ? sm[tid - off] : 0;
        __syncthreads();
        sm[tid] += t;
        __syncthreads();
    }
    if (i < N_NODES) offs[i + 1] = sm[tid];
    if (tid == 1023) btot[blockIdx.x] = sm[1023];
}
// scan3 with the 30-block prefix computed inline (merges old scan2)
__global__ __launch_bounds__(1024) void scan3_k(const int* __restrict__ cnt,
                                                int* __restrict__ offs,
                                                int* __restrict__ cursor,
                                                const int* __restrict__ btot,
                                                int nb)
{
    __shared__ int bp_s;
    if (threadIdx.x < 64) {
        int lane = threadIdx.x;
        int orig = (lane < nb) ? btot[lane] : 0;
        int v = orig;
        for (int off = 1; off < 64; off <<= 1) {
            int t = __shfl_up(v, off);
            if (lane >= off) v += t;
        }
        if (lane == (int)blockIdx.x) bp_s = v - orig;   // exclusive prefix
    }
    __syncthreads();
    int bpref = bp_s;
    int i = blockIdx.x * 1024 + threadIdx.x;
    if (i < N_NODES) {
        int inc = offs[i + 1] + bpref;
        offs[i + 1] = inc;
        cursor[i]   = inc - cnt[i];
    }
    if (i == 0) offs[0] = 0;
}
__global__ void scatter_k(const int* __restrict__ ei, int* __restrict__ cursor,
                          int* __restrict__ ssrc)
{
    int i = blockIdx.x*blockDim.x + threadIdx.x;
    if (i >= TOT_E) return;
    int s, d;
    if (i < N_EDGES) { s = ei[i]; d = ei[N_EDGES + i]; }
    else             { s = i - N_EDGES; d = s; }
    int pos = atomicAdd(&cursor[d], 1);
    ssrc[pos] = s;
}

// ---------------- layer-1 aggregate-first: aggx[n,h,:] = sum alpha_h x[src] -
__global__ __launch_bounds__(64) void aggx_k(
    const u16* __restrict__ xb,
    const float* __restrict__ als,
    const float* __restrict__ ald,
    const int* __restrict__ offs,
    const int* __restrict__ ssrc,
    u16* __restrict__ aggx)
{
    const int n = blockIdx.x, tid = threadIdx.x;
    const int beg = offs[n], end = offs[n+1];

    float aldh[4];
#pragma unroll
    for (int h = 0; h < 4; ++h) aldh[h] = ald[(size_t)n*4 + h];

    // denom sweep
    float lsum[4] = {0.f, 0.f, 0.f, 0.f};
    for (int e = beg + tid; e < end; e += 64) {
        int s = ssrc[e];
        float4 a = *(const float4*)(als + (size_t)s*4);
        float la[4] = {a.x, a.y, a.z, a.w};
#pragma unroll
        for (int h = 0; h < 4; ++h) {
            float l = la[h] + aldh[h];
            l = (l >= 0.f) ? l : 0.2f*l;
            lsum[h] += __expf(l);
        }
    }
#pragma unroll
    for (int h = 0; h < 4; ++h)
#pragma unroll
        for (int o = 32; o > 0; o >>= 1) lsum[h] += __shfl_xor(lsum[h], o);
    float inv[4];
#pragma unroll
    for (int h = 0; h < 4; ++h) inv[h] = 1.0f / lsum[h];

    // chunk-staged gather of x rows, 4-head accumulate
    __shared__ int    sh_s[64];
    __shared__ float4 sh_w[64];
    const int c0 = tid * 4;
    float acc[4][4] = {};
    for (int chunk = beg; chunk < end; chunk += 64) {
        int e = chunk + tid;
        if (e < end) {
            int s = ssrc[e];
            sh_s[tid] = s;
            float4 a = *(const float4*)(als + (size_t)s*4);
            float la[4] = {a.x, a.y, a.z, a.w};
            float wv[4];
#pragma unroll
            for (int h = 0; h < 4; ++h) {
                float l = la[h] + aldh[h];
                l = (l >= 0.f) ? l : 0.2f*l;
                wv[h] = __expf(l) * inv[h];
            }
            sh_w[tid] = make_float4(wv[0], wv[1], wv[2], wv[3]);
        }
        __syncthreads();
        int cnt2 = min(64, end - chunk);
        int j = 0;
        for (; j + 4 <= cnt2; j += 4) {
            int s0 = sh_s[j+0], s1 = sh_s[j+1], s2 = sh_s[j+2], s3 = sh_s[j+3];
            float4 w0 = sh_w[j+0], w1 = sh_w[j+1], w2 = sh_w[j+2], w3 = sh_w[j+3];
            ushort4 v0 = *(const ushort4*)(xb + (size_t)s0*IN_CH + c0);
            ushort4 v1 = *(const ushort4*)(xb + (size_t)s1*IN_CH + c0);
            ushort4 v2 = *(const ushort4*)(xb + (size_t)s2*IN_CH + c0);
            ushort4 v3 = *(const ushort4*)(xb + (size_t)s3*IN_CH + c0);
            float x0[4] = {bf2f(v0.x), bf2f(v0.y), bf2f(v0.z), bf2f(v0.w)};
            float x1[4] = {bf2f(v1.x), bf2f(v1.y), bf2f(v1.z), bf2f(v1.w)};
            float x2[4] = {bf2f(v2.x), bf2f(v2.y), bf2f(v2.z), bf2f(v2.w)};
            float x3[4] = {bf2f(v3.x), bf2f(v3.y), bf2f(v3.z), bf2f(v3.w)};
            float wa0[4] = {w0.x, w0.y, w0.z, w0.w};
            float wa1[4] = {w1.x, w1.y, w1.z, w1.w};
            float wa2[4] = {w2.x, w2.y, w2.z, w2.w};
            float wa3[4] = {w3.x, w3.y, w3.z, w3.w};
#pragma unroll
            for (int h = 0; h < 4; ++h)
#pragma unroll
                for (int k = 0; k < 4; ++k)
                    acc[h][k] += wa0[h]*x0[k] + wa1[h]*x1[k]
                               + wa2[h]*x2[k] + wa3[h]*x3[k];
        }
        for (; j < cnt2; ++j) {
            int s0 = sh_s[j];
            float4 w0 = sh_w[j];
            ushort4 v0 = *(const ushort4*)(xb + (size_t)s0*IN_CH + c0);
            float x0[4] = {bf2f(v0.x), bf2f(v0.y), bf2f(v0.z), bf2f(v0.w)};
            float wa[4] = {w0.x, w0.y, w0.z, w0.w};
#pragma unroll
            for (int h = 0; h < 4; ++h)
#pragma unroll
                for (int k = 0; k < 4; ++k)
                    acc[h][k] += wa[h]*x0[k];
        }
        __syncthreads();
    }

    u16* op = aggx + (size_t)n * 1024;
#pragma unroll
    for (int h = 0; h < 4; ++h) {
        ushort4 o;
        o.x = f2bf(acc[h][0]); o.y = f2bf(acc[h][1]);
        o.z = f2bf(acc[h][2]); o.w = f2bf(acc[h][3]);
        *(ushort4*)(op + h*256 + c0) = o;
    }
}

// ---------------- per-dst softmax + weighted aggregation (layer 2) ----------
template<int H, int C, int VW, bool PRELU, int OUTMODE>
__global__ __launch_bounds__(64) void aggregate_k(
    const u16* __restrict__ hb,
    const float* __restrict__ als,
    const float* __restrict__ ald,
    const int* __restrict__ offs,
    const int* __restrict__ ssrc,
    const float* __restrict__ bias,
    const float* __restrict__ prelu_w,
    void* __restrict__ outv,
    const int* __restrict__ flag)
{
    constexpr int CT = H * C;
    constexpr int T  = 64;
    static_assert(CT == T * VW, "geometry");
    const int n   = blockIdx.x;
    const int tid = threadIdx.x;
    const int beg = offs[n], end = offs[n+1];

    float aldh[H];
#pragma unroll
    for (int h = 0; h < H; ++h) aldh[h] = ald[(size_t)n*H + h];

    float lsum[H];
#pragma unroll
    for (int h = 0; h < H; ++h) lsum[h] = 0.f;
    for (int e = beg + tid; e < end; e += T) {
        int s = ssrc[e];
#pragma unroll
        for (int h = 0; h < H; ++h) {
            float l = als[(size_t)s*H + h] + aldh[h];
            l = (l >= 0.f) ? l : 0.2f*l;
            lsum[h] += __expf(l);
        }
    }
#pragma unroll
    for (int h = 0; h < H; ++h) {
#pragma unroll
        for (int o = 32; o > 0; o >>= 1) lsum[h] += __shfl_xor(lsum[h], o);
    }
    float inv[H];
#pragma unroll
    for (int h = 0; h < H; ++h) inv[h] = 1.0f / lsum[h];

    __shared__ int   sh_s[T];
    __shared__ float sh_w[H][T];
    const int hh = (VW * tid) / C;
    float acc[VW];
#pragma unroll
    for (int k = 0; k < VW; ++k) acc[k] = 0.f;

    for (int chunk = beg; chunk < end; chunk += T) {
        int e = chunk + tid;
        if (e < end) {
            int s = ssrc[e];
            sh_s[tid] = s;
#pragma unroll
            for (int h = 0; h < H; ++h) {
                float l = als[(size_t)s*H + h] + aldh[h];
                l = (l >= 0.f) ? l : 0.2f*l;
                sh_w[h][tid] = __expf(l) * inv[h];
            }
        }
        __syncthreads();
        int cnt2 = min(T, end - chunk);
        int j = 0;
        for (; j + 4 <= cnt2; j += 4) {
            int   s0 = sh_s[j+0], s1 = sh_s[j+1], s2 = sh_s[j+2], s3 = sh_s[j+3];
            float w0 = sh_w[hh][j+0], w1 = sh_w[hh][j+1];
            float w2 = sh_w[hh][j+2], w3 = sh_w[hh][j+3];
            if constexpr (VW == 8) {
                u16x8 v0 = *(const u16x8*)(hb + (size_t)s0*CT + VW*tid);
                u16x8 v1 = *(const u16x8*)(hb + (size_t)s1*CT + VW*tid);
                u16x8 v2 = *(const u16x8*)(hb + (size_t)s2*CT + VW*tid);
                u16x8 v3 = *(const u16x8*)(hb + (size_t)s3*CT + VW*tid);
#pragma unroll
                for (int k = 0; k < 8; ++k) {
                    acc[k] += w0*bf2f(v0[k]) + w1*bf2f(v1[k])
                            + w2*bf2f(v2[k]) + w3*bf2f(v3[k]);
                }
            } else {
                ushort4 v0 = *(const ushort4*)(hb + (size_t)s0*CT + VW*tid);
                ushort4 v1 = *(const ushort4*)(hb + (size_t)s1*CT + VW*tid);
                ushort4 v2 = *(const ushort4*)(hb + (size_t)s2*CT + VW*tid);
                ushort4 v3 = *(const ushort4*)(hb + (size_t)s3*CT + VW*tid);
                acc[0] += w0*bf2f(v0.x) + w1*bf2f(v1.x) + w2*bf2f(v2.x) + w3*bf2f(v3.x);
                acc[1] += w0*bf2f(v0.y) + w1*bf2f(v1.y) + w2*bf2f(v2.y) + w3*bf2f(v3.y);
                acc[2] += w0*bf2f(v0.z) + w1*bf2f(v1.z) + w2*bf2f(v2.z) + w3*bf2f(v3.z);
                acc[3] += w0*bf2f(v0.w) + w1*bf2f(v1.w) + w2*bf2f(v2.w) + w3*bf2f(v3.w);
            }
        }
        for (; j < cnt2; ++j) {
            int s0 = sh_s[j];
            float w0 = sh_w[hh][j];
            if constexpr (VW == 8) {
                u16x8 v0 = *(const u16x8*)(hb + (size_t)s0*CT + VW*tid);
#pragma unroll
                for (int k = 0; k < 8; ++k) acc[k] += w0*bf2f(v0[k]);
            } else {
                ushort4 v0 = *(const ushort4*)(hb + (size_t)s0*CT + VW*tid);
                acc[0] += w0*bf2f(v0.x); acc[1] += w0*bf2f(v0.y);
                acc[2] += w0*bf2f(v0.z); acc[3] += w0*bf2f(v0.w);
            }
        }
        __syncthreads();
    }

#pragma unroll
    for (int k = 0; k < VW; ++k) acc[k] += bias[VW*tid + k];
    if (PRELU) {
        float pw = *prelu_w;
#pragma unroll
        for (int k = 0; k < VW; ++k) acc[k] = (acc[k] >= 0.f) ? acc[k] : pw*acc[k];
    }
    size_t ofs = (size_t)n*CT + VW*tid;
    bool bf = (OUTMODE == 1) || (OUTMODE == 2 && *flag);
    if (bf) {
        if constexpr (VW == 8) {
            u16x8 o;
#pragma unroll
            for (int k = 0; k < 8; ++k) o[k] = f2bf(acc[k]);
            *(u16x8*)((u16*)outv + ofs) = o;
        } else {
            ushort4 o; o.x=f2bf(acc[0]); o.y=f2bf(acc[1]); o.z=f2bf(acc[2]); o.w=f2bf(acc[3]);
            *(ushort4*)((u16*)outv + ofs) = o;
        }
    } else {
        float* op = (float*)outv + ofs;
#pragma unroll
        for (int k = 0; k < VW; k += 4)
            *(float4*)(op + k) = make_float4(acc[k], acc[k+1], acc[k+2], acc[k+3]);
    }
}

// ---------------------------------------------------------------------------
extern "C" void kernel_launch(void* const* d_in, const int* in_sizes, int n_in,
                              void* d_out, int out_size, void* d_ws, size_t ws_size,
                              hipStream_t stream)
{
    const void* x   = d_in[0];
    const int*  ei  = (const int*)d_in[1];
    const void* W1  = d_in[2];
    const void* as1 = d_in[3];
    const void* ad1 = d_in[4];
    const void* b1  = d_in[5];
    const void* pw  = d_in[6];
    const void* W2  = d_in[7];
    const void* as2 = d_in[8];
    const void* ad2 = d_in[9];
    const void* b2  = d_in[10];

    float* ws = (float*)d_ws;
    int*   flag = (int*)ws;                               // 16 slots
    float* as1f = ws + 16;                                // 512
    float* ad1f = as1f + 512;                             // 512
    float* b1f  = ad1f + 512;                             // 512
    float* as2f = b1f  + 512;                             // 256
    float* ad2f = as2f + 256;                             // 256
    float* b2f  = ad2f + 256;                             // 256
    float* pwf  = b2f  + 256;                             // 16
    float* vsd  = pwf + 16;                               // 2048 (8x256)
    u16*   W1t  = (u16*)(vsd + 2048);                     // 131072 u16
    u16*   W2t  = W1t + IN_CH*HEADS*HID;                  // 131072 u16
    float* als1 = (float*)(W2t + HEADS*HID*OUT_CH);       // 120000
    float* ald1 = als1 + (size_t)N_NODES*HEADS;           // 120000
    // zero region: als2v, ald2v, cnt contiguous (90000 ints)
    float* als2v = ald1 + (size_t)N_NODES*HEADS;          // 30000
    float* ald2v = als2v + N_NODES;                       // 30000
    int*   cnt    = (int*)(ald2v + N_NODES);              // 30000
    int*   offs   = cnt + N_NODES;                        // 30004 (pad)
    int*   cursor = offs + 30004;                         // 30000
    int*   btot   = cursor + N_NODES;                     // 32
    int*   bpref  = btot + 32;                            // 36 (unused, kept for layout)
    int*   ssrc   = bpref + 36;                           // 510004
    u16*   xb     = (u16*)(ssrc + 510004);                // 30000*256 u16
    u16*   aggx   = xb + (size_t)N_NODES*IN_CH;           // 30000*1024 u16
    u16*   h1pb   = aggx + (size_t)N_NODES*1024;          // 30000*512 u16
    u16*   h2b    = aggx;  // alias: aggx dead after gemm_h1

    const int NB = (N_NODES + 1023) / 1024;   // 30 scan blocks
    const int CB = (TOT_E + 255) / 256;       // 1993 count blocks

    // dtype detect, then one consolidated conversion/zero/vsd launch
    detect_k<<<1, 256, 0, stream>>>((const unsigned int*)x, flag);
    wconv_k<<<1394, 256, 0, stream>>>(W1, W2, as1, ad1, b1, as2, ad2, b2, pw,
                                      W1t, W2t, as1f, ad1f, b1f, as2f, ad2f, b2f, pwf,
                                      (int*)als2v, vsd, flag);

    // fused x-convert + layer-1 logits + CSR count
    xprep_k<<<XPB + CB, 256, 0, stream>>>(x, vsd, xb, als1, ald1, ei, cnt, flag);

    // CSR scan (scan2 folded into scan3) + scatter
    scan1_k  <<<NB, 1024, 0, stream>>>(cnt, offs, btot);
    scan3_k  <<<NB, 1024, 0, stream>>>(cnt, offs, cursor, btot, NB);
    scatter_k<<<CB, 256, 0, stream>>>(ei, cursor, ssrc);

    // ---- layer 1 (aggregate-first) ----
    aggx_k<<<N_NODES, 64, 0, stream>>>(xb, als1, ald1, offs, ssrc, aggx);
    dim3 gh1(1, (N_NODES+127)/128, HEADS);
    gemm_h1_k<<<gh1, 256, 0, stream>>>(aggx, W1t, h1pb, b1f, pwf, N_NODES);

    // ---- layer 2 ----
    dim3 g2(256/128, (N_NODES+127)/128);
    gemm_bf_k<<<g2, 256, 0, stream>>>(h1pb, W2t, h2b, as2f, ad2f, als2v, ald2v,
                                      N_NODES, OUT_CH, HEADS*HID, 1, 8);
    aggregate_k<1, OUT_CH, 4, false, 2>
        <<<N_NODES, 64, 0, stream>>>(h2b, als2v, ald2v, offs, ssrc, b2f, nullptr, d_out, flag);
}

// Round 12
// 329.443 us; speedup vs baseline: 1.0626x; 1.0626x over previous
//
#include <hip/hip_runtime.h>
#include <hip/hip_bf16.h>
#include <float.h>

#define N_NODES 30000
#define IN_CH   256
#define HID     128
#define HEADS   4
#define OUT_CH  256
#define N_EDGES 480000
#define TOT_E   (N_EDGES + N_NODES)

typedef unsigned short u16;   // bf16 bits
typedef __attribute__((ext_vector_type(8))) unsigned short u16x8;
typedef __attribute__((ext_vector_type(8))) short          s16x8;  // MFMA A/B frag (8 bf16)
typedef __attribute__((ext_vector_type(4))) float          f32x4;  // MFMA C/D frag

__device__ inline float bf2f(u16 u) {
    union { unsigned int i; float f; } v; v.i = ((unsigned int)u) << 16; return v.f;
}
__device__ inline u16 f2bf(float f) {
    union { float f; unsigned int i; } u; u.f = f;
    unsigned int r = u.i + 0x7FFF + ((u.i >> 16) & 1);
    return (u16)(r >> 16);
}

// ---------- dtype detection: bf16 exponent field vs fp32 mantissa bits -----
__global__ void detect_k(const unsigned int* __restrict__ w, int* __restrict__ flag) {
    __shared__ int votes;
    if (threadIdx.x == 0) votes = 0;
    __syncthreads();
    int v = 0;
    for (int i = threadIdx.x; i < 2048; i += 256) {
        unsigned int e = (w[i] >> 7) & 0xFFu;
        if (e >= 100u && e <= 140u) v++;
    }
    atomicAdd(&votes, v);
    __syncthreads();
    if (threadIdx.x == 0) *flag = (votes > 1024) ? 1 : 0;
}

// ---------- one-launch conversion + zero (block-range dispatch) -------------
// blocks [0,512):     W1 [256][512] -> W1t [512][256] bf16
// blocks [512,1024):  W2 [512][256] -> W2t [256][512] bf16
// blocks [1024,1034): 7 small vectors -> fp32 (2305 elems)
// blocks [1034,1386): zero 90000 ints (als2v, ald2v, cnt)
// NOTE: vsd computation deliberately NOT folded here — reading raw W1 with
// lane-stride 512 is uncoalesced (64 lines/load x 128 iters on 8 blocks)
// and serialized the whole launch in round 11 (+15 us). prep_av_k below
// reads the transposed W1t coalesced instead.
__global__ void wconv_k(const void* __restrict__ W1, const void* __restrict__ W2,
                        const void* __restrict__ as1, const void* __restrict__ ad1,
                        const void* __restrict__ b1,  const void* __restrict__ as2,
                        const void* __restrict__ ad2, const void* __restrict__ b2,
                        const void* __restrict__ pw,
                        u16* __restrict__ W1t, u16* __restrict__ W2t,
                        float* __restrict__ as1f, float* __restrict__ ad1f,
                        float* __restrict__ b1f,  float* __restrict__ as2f,
                        float* __restrict__ ad2f, float* __restrict__ b2f,
                        float* __restrict__ pwf,
                        int* __restrict__ zeroreg,
                        const int* __restrict__ flag)
{
    int b = blockIdx.x, t = threadIdx.x;
    int f = *flag;
    if (b < 512) {
        int idx = b*256 + t;                 // 0..131071
        int r = idx >> 9, c = idx & 511;     // W1 [256][512]
        u16 v = f ? ((const u16*)W1)[idx] : f2bf(((const float*)W1)[idx]);
        W1t[(size_t)c*256 + r] = v;
    } else if (b < 1024) {
        int idx = (b-512)*256 + t;           // 0..131071
        int r = idx >> 8, c = idx & 255;     // W2 [512][256]
        u16 v = f ? ((const u16*)W2)[idx] : f2bf(((const float*)W2)[idx]);
        W2t[(size_t)c*512 + r] = v;
    } else if (b < 1034) {
        int i = (b-1024)*256 + t;            // 0..2559
#define CV(in, k) (f ? bf2f(((const u16*)(in))[k]) : ((const float*)(in))[k])
        if      (i < 512)  as1f[i]        = CV(as1, i);
        else if (i < 1024) ad1f[i - 512]  = CV(ad1, i - 512);
        else if (i < 1536) b1f [i - 1024] = CV(b1,  i - 1024);
        else if (i < 1792) as2f[i - 1536] = CV(as2, i - 1536);
        else if (i < 2048) ad2f[i - 1792] = CV(ad2, i - 1792);
        else if (i < 2304) b2f [i - 2048] = CV(b2,  i - 2048);
        else if (i == 2304) pwf[0]        = CV(pw, 0);
#undef CV
    } else {
        int i = (b-1034)*256 + t;
        if (i < 90000) zeroreg[i] = 0;
    }
}

// ---------- vsd[v][k] = sum_c W1t[(h*128+c)*256+k] * a[h][c] (coalesced) ----
// v: 0-3 src heads, 4-7 dst heads. Lane index = k -> contiguous W1t reads.
__global__ __launch_bounds__(256) void prep_av_k(
    const u16* __restrict__ W1t, const float* __restrict__ as1f,
    const float* __restrict__ ad1f, float* __restrict__ vsd)
{
    int idx = blockIdx.x * 256 + threadIdx.x;    // 0..2047
    if (idx >= 2048) return;
    int v = idx >> 8;
    int k = idx & 255;
    int h = v & 3;
    const float* av = (v < 4) ? as1f : ad1f;
    float s = 0.f;
    for (int c = 0; c < 128; ++c)
        s += bf2f(W1t[(size_t)(h*128 + c)*256 + k]) * av[h*128 + c];
    vsd[idx] = s;
}

// ---------- fused x convert + layer-1 logits + CSR count --------------------
// blocks [0, 7500): 4 nodes per block (one wave each) — converts x -> xb and
//   computes als1/ald1 from POST-ROUNDING bf16 values (bit-exact parity).
// blocks [7500, 7500+1993): degree count (atomicAdd into cnt).
#define XPB 7500
__global__ __launch_bounds__(256) void xprep_k(
    const void* __restrict__ x, const float* __restrict__ vsd,
    u16* __restrict__ xb, float* __restrict__ als, float* __restrict__ ald,
    const int* __restrict__ ei, int* __restrict__ cnt,
    const int* __restrict__ flag)
{
    int b = blockIdx.x;
    if (b >= XPB) {
        int i = (b - XPB)*256 + threadIdx.x;
        if (i < TOT_E) {
            int d = (i < N_EDGES) ? ei[N_EDGES + i] : (i - N_EDGES);
            atomicAdd(&cnt[d], 1);
        }
        return;
    }
    int n = b * 4 + (threadIdx.x >> 6);
    int lane = threadIdx.x & 63;
    if (n >= N_NODES) return;
    int c0 = lane * 4;
    u16 xr[4];
    if (*flag) {
        ushort4 v = *(const ushort4*)((const u16*)x + (size_t)n*IN_CH + c0);
        xr[0]=v.x; xr[1]=v.y; xr[2]=v.z; xr[3]=v.w;
    } else {
        float4 v = *(const float4*)((const float*)x + (size_t)n*IN_CH + c0);
        xr[0]=f2bf(v.x); xr[1]=f2bf(v.y); xr[2]=f2bf(v.z); xr[3]=f2bf(v.w);
    }
    ushort4 o; o.x=xr[0]; o.y=xr[1]; o.z=xr[2]; o.w=xr[3];
    *(ushort4*)(xb + (size_t)n*IN_CH + c0) = o;
    float x0=bf2f(xr[0]), x1=bf2f(xr[1]), x2=bf2f(xr[2]), x3=bf2f(xr[3]);
#pragma unroll
    for (int v = 0; v < 8; ++v) {
        float4 vv = *(const float4*)(vsd + v*256 + c0);
        float d = x0*vv.x + x1*vv.y + x2*vv.z + x3*vv.w;
#pragma unroll
        for (int o2 = 32; o2 > 0; o2 >>= 1) d += __shfl_xor(d, o2);
        if (lane == 0) {
            if (v < 4) als[(size_t)n*4 + v]     = d;
            else       ald[(size_t)n*4 + v - 4] = d;
        }
    }
}

// ---------------- MFMA GEMM + fused logits epilogue (layer 2) --------------
__global__ __launch_bounds__(256) void gemm_bf_k(const u16* __restrict__ A,
                                                 const u16* __restrict__ Bt,
                                                 u16* __restrict__ Cb,
                                                 const float* __restrict__ a_s,
                                                 const float* __restrict__ a_d,
                                                 float* __restrict__ als,
                                                 float* __restrict__ ald,
                                                 int M, int N, int K,
                                                 int H, int hshift)
{
    __shared__ __align__(16) u16 As[128][40];
    __shared__ __align__(16) u16 Bs[128][40];

    const int tid  = threadIdx.x;
    const int wid  = tid >> 6;
    const int lane = tid & 63;
    const int wr   = wid >> 1;
    const int wc   = wid & 1;
    const int lr   = lane & 15;
    const int lg   = lane >> 4;
    const int row0 = blockIdx.y * 128;
    const int col0 = blockIdx.x * 128;

    const int st_r = tid >> 1;
    const int st_c = (tid & 1) << 4;

    f32x4 acc[4][4];
#pragma unroll
    for (int i = 0; i < 4; ++i)
#pragma unroll
        for (int j = 0; j < 4; ++j)
            acc[i][j] = (f32x4){0.f, 0.f, 0.f, 0.f};

    for (int k0 = 0; k0 < K; k0 += 32) {
        __syncthreads();
        {
            u16x8 a0 = {}, a1 = {};
            int ar = row0 + st_r;
            if (ar < M) {
                const u16* ap = A + (size_t)ar * K + k0 + st_c;
                a0 = *(const u16x8*)ap;
                a1 = *(const u16x8*)(ap + 8);
            }
            *(u16x8*)&As[st_r][st_c]     = a0;
            *(u16x8*)&As[st_r][st_c + 8] = a1;
            const u16* bp = Bt + (size_t)(col0 + st_r) * K + k0 + st_c;
            *(u16x8*)&Bs[st_r][st_c]     = *(const u16x8*)bp;
            *(u16x8*)&Bs[st_r][st_c + 8] = *(const u16x8*)(bp + 8);
        }
        __syncthreads();

        s16x8 af[4], bf[4];
#pragma unroll
        for (int mf = 0; mf < 4; ++mf)
            af[mf] = *(const s16x8*)&As[wr*64 + mf*16 + lr][lg*8];
#pragma unroll
        for (int nf = 0; nf < 4; ++nf)
            bf[nf] = *(const s16x8*)&Bs[wc*64 + nf*16 + lr][lg*8];
#pragma unroll
        for (int mf = 0; mf < 4; ++mf)
#pragma unroll
            for (int nf = 0; nf < 4; ++nf)
                acc[mf][nf] = __builtin_amdgcn_mfma_f32_16x16x32_bf16(
                    af[mf], bf[nf], acc[mf][nf], 0, 0, 0);
    }

    const int head = (col0 + wc*64) >> hshift;
    float asj[4], adj[4];
#pragma unroll
    for (int nf = 0; nf < 4; ++nf) {
        int j = col0 + wc*64 + nf*16 + lr;
        asj[nf] = a_s[j];
        adj[nf] = a_d[j];
    }
#pragma unroll
    for (int mf = 0; mf < 4; ++mf) {
#pragma unroll
        for (int r = 0; r < 4; ++r) {
            int rr = row0 + wr*64 + mf*16 + lg*4 + r;
            float ss = 0.f, sd = 0.f;
#pragma unroll
            for (int nf = 0; nf < 4; ++nf) {
                float v = acc[mf][nf][r];
                ss += v * asj[nf];
                sd += v * adj[nf];
            }
#pragma unroll
            for (int m2 = 1; m2 < 16; m2 <<= 1) {
                ss += __shfl_xor(ss, m2);
                sd += __shfl_xor(sd, m2);
            }
            if (rr < M) {
                if (lr == 0) {
                    atomicAdd(&als[(size_t)rr * H + head], ss);
                    atomicAdd(&ald[(size_t)rr * H + head], sd);
                }
                size_t base = (size_t)rr * N + col0 + wc*64 + lr;
#pragma unroll
                for (int nf = 0; nf < 4; ++nf)
                    Cb[base + nf*16] = f2bf(acc[mf][nf][r]);
            }
        }
    }
}

// ---------------- head-blocked MFMA GEMM (layer 1): h1p = aggx_h @ W1_h -----
__global__ __launch_bounds__(256) void gemm_h1_k(const u16* __restrict__ A,
                                                 const u16* __restrict__ Bt,
                                                 u16* __restrict__ Cb,
                                                 const float* __restrict__ bias,
                                                 const float* __restrict__ prelu_w,
                                                 int M)
{
    __shared__ __align__(16) u16 As[128][40];
    __shared__ __align__(16) u16 Bs[128][40];

    const int h    = blockIdx.z;
    const int tid  = threadIdx.x;
    const int wid  = tid >> 6;
    const int lane = tid & 63;
    const int wr   = wid >> 1;
    const int wc   = wid & 1;
    const int lr   = lane & 15;
    const int lg   = lane >> 4;
    const int row0 = blockIdx.y * 128;

    const int st_r = tid >> 1;
    const int st_c = (tid & 1) << 4;

    f32x4 acc[4][4];
#pragma unroll
    for (int i = 0; i < 4; ++i)
#pragma unroll
        for (int j = 0; j < 4; ++j)
            acc[i][j] = (f32x4){0.f, 0.f, 0.f, 0.f};

    for (int k0 = 0; k0 < 256; k0 += 32) {
        __syncthreads();
        {
            u16x8 a0 = {}, a1 = {};
            int ar = row0 + st_r;
            if (ar < M) {
                const u16* ap = A + (size_t)ar * 1024 + h*256 + k0 + st_c;
                a0 = *(const u16x8*)ap;
                a1 = *(const u16x8*)(ap + 8);
            }
            *(u16x8*)&As[st_r][st_c]     = a0;
            *(u16x8*)&As[st_r][st_c + 8] = a1;
            const u16* bp = Bt + (size_t)(h*128 + st_r) * 256 + k0 + st_c;
            *(u16x8*)&Bs[st_r][st_c]     = *(const u16x8*)bp;
            *(u16x8*)&Bs[st_r][st_c + 8] = *(const u16x8*)(bp + 8);
        }
        __syncthreads();

        s16x8 af[4], bf[4];
#pragma unroll
        for (int mf = 0; mf < 4; ++mf)
            af[mf] = *(const s16x8*)&As[wr*64 + mf*16 + lr][lg*8];
#pragma unroll
        for (int nf = 0; nf < 4; ++nf)
            bf[nf] = *(const s16x8*)&Bs[wc*64 + nf*16 + lr][lg*8];
#pragma unroll
        for (int mf = 0; mf < 4; ++mf)
#pragma unroll
            for (int nf = 0; nf < 4; ++nf)
                acc[mf][nf] = __builtin_amdgcn_mfma_f32_16x16x32_bf16(
                    af[mf], bf[nf], acc[mf][nf], 0, 0, 0);
    }

    const float pw = *prelu_w;
#pragma unroll
    for (int mf = 0; mf < 4; ++mf) {
#pragma unroll
        for (int r = 0; r < 4; ++r) {
            int rr = row0 + wr*64 + mf*16 + lg*4 + r;
            if (rr >= M) continue;
            size_t base = (size_t)rr * 512 + h*128 + wc*64 + lr;
#pragma unroll
            for (int nf = 0; nf < 4; ++nf) {
                int j = wc*64 + nf*16 + lr;
                float v = acc[mf][nf][r] + bias[h*128 + j];
                v = (v >= 0.f) ? v : pw * v;
                Cb[base + nf*16] = f2bf(v);
            }
        }
    }
}

// ---------------- CSR build (count lives in xprep_k) ------------------------
__global__ __launch_bounds__(1024) void scan1_k(const int* __restrict__ cnt,
                                                int* __restrict__ offs,
                                                int* __restrict__ btot)
{
    __shared__ int sm[1024];
    int tid = threadIdx.x;
    int i = blockIdx.x * 1024 + tid;
    int v = (i < N_NODES) ? cnt[i] : 0;
    sm[tid] = v;
    __syncthreads();
    for (int off = 1; off < 1024; off <<= 1) {
        int t = (tid >= off) ? sm[tid - off] : 0;
        __syncthreads();
        sm[tid] += t;
        __syncthreads();
    }
    if (i < N_NODES) offs[i + 1] = sm[tid];
    if (tid == 1023) btot[blockIdx.x] = sm[1023];
}
// scan3 with the 30-block prefix computed inline (merges old scan2)
__global__ __launch_bounds__(1024) void scan3_k(const int* __restrict__ cnt,
                                                int* __restrict__ offs,
                                                int* __restrict__ cursor,
                                                const int* __restrict__ btot,
                                                int nb)
{
    __shared__ int bp_s;
    if (threadIdx.x < 64) {
        int lane = threadIdx.x;
        int orig = (lane < nb) ? btot[lane] : 0;
        int v = orig;
        for (int off = 1; off < 64; off <<= 1) {
            int t = __shfl_up(v, off);
            if (lane >= off) v += t;
        }
        if (lane == (int)blockIdx.x) bp_s = v - orig;   // exclusive prefix
    }
    __syncthreads();
    int bpref = bp_s;
    int i = blockIdx.x * 1024 + threadIdx.x;
    if (i < N_NODES) {
        int inc = offs[i + 1] + bpref;
        offs[i + 1] = inc;
        cursor[i]   = inc - cnt[i];
    }
    if (i == 0) offs[0] = 0;
}
__global__ void scatter_k(const int* __restrict__ ei, int* __restrict__ cursor,
                          int* __restrict__ ssrc)
{
    int i = blockIdx.x*blockDim.x + threadIdx.x;
    if (i >= TOT_E) return;
    int s, d;
    if (i < N_EDGES) { s = ei[i]; d = ei[N_EDGES + i]; }
    else             { s = i - N_EDGES; d = s; }
    int pos = atomicAdd(&cursor[d], 1);
    ssrc[pos] = s;
}

// ---------------- layer-1 aggregate-first: aggx[n,h,:] = sum alpha_h x[src] -
__global__ __launch_bounds__(64) void aggx_k(
    const u16* __restrict__ xb,
    const float* __restrict__ als,
    const float* __restrict__ ald,
    const int* __restrict__ offs,
    const int* __restrict__ ssrc,
    u16* __restrict__ aggx)
{
    const int n = blockIdx.x, tid = threadIdx.x;
    const int beg = offs[n], end = offs[n+1];

    float aldh[4];
#pragma unroll
    for (int h = 0; h < 4; ++h) aldh[h] = ald[(size_t)n*4 + h];

    // denom sweep
    float lsum[4] = {0.f, 0.f, 0.f, 0.f};
    for (int e = beg + tid; e < end; e += 64) {
        int s = ssrc[e];
        float4 a = *(const float4*)(als + (size_t)s*4);
        float la[4] = {a.x, a.y, a.z, a.w};
#pragma unroll
        for (int h = 0; h < 4; ++h) {
            float l = la[h] + aldh[h];
            l = (l >= 0.f) ? l : 0.2f*l;
            lsum[h] += __expf(l);
        }
    }
#pragma unroll
    for (int h = 0; h < 4; ++h)
#pragma unroll
        for (int o = 32; o > 0; o >>= 1) lsum[h] += __shfl_xor(lsum[h], o);
    float inv[4];
#pragma unroll
    for (int h = 0; h < 4; ++h) inv[h] = 1.0f / lsum[h];

    // chunk-staged gather of x rows, 4-head accumulate
    __shared__ int    sh_s[64];
    __shared__ float4 sh_w[64];
    const int c0 = tid * 4;
    float acc[4][4] = {};
    for (int chunk = beg; chunk < end; chunk += 64) {
        int e = chunk + tid;
        if (e < end) {
            int s = ssrc[e];
            sh_s[tid] = s;
            float4 a = *(const float4*)(als + (size_t)s*4);
            float la[4] = {a.x, a.y, a.z, a.w};
            float wv[4];
#pragma unroll
            for (int h = 0; h < 4; ++h) {
                float l = la[h] + aldh[h];
                l = (l >= 0.f) ? l : 0.2f*l;
                wv[h] = __expf(l) * inv[h];
            }
            sh_w[tid] = make_float4(wv[0], wv[1], wv[2], wv[3]);
        }
        __syncthreads();
        int cnt2 = min(64, end - chunk);
        int j = 0;
        for (; j + 4 <= cnt2; j += 4) {
            int s0 = sh_s[j+0], s1 = sh_s[j+1], s2 = sh_s[j+2], s3 = sh_s[j+3];
            float4 w0 = sh_w[j+0], w1 = sh_w[j+1], w2 = sh_w[j+2], w3 = sh_w[j+3];
            ushort4 v0 = *(const ushort4*)(xb + (size_t)s0*IN_CH + c0);
            ushort4 v1 = *(const ushort4*)(xb + (size_t)s1*IN_CH + c0);
            ushort4 v2 = *(const ushort4*)(xb + (size_t)s2*IN_CH + c0);
            ushort4 v3 = *(const ushort4*)(xb + (size_t)s3*IN_CH + c0);
            float x0[4] = {bf2f(v0.x), bf2f(v0.y), bf2f(v0.z), bf2f(v0.w)};
            float x1[4] = {bf2f(v1.x), bf2f(v1.y), bf2f(v1.z), bf2f(v1.w)};
            float x2[4] = {bf2f(v2.x), bf2f(v2.y), bf2f(v2.z), bf2f(v2.w)};
            float x3[4] = {bf2f(v3.x), bf2f(v3.y), bf2f(v3.z), bf2f(v3.w)};
            float wa0[4] = {w0.x, w0.y, w0.z, w0.w};
            float wa1[4] = {w1.x, w1.y, w1.z, w1.w};
            float wa2[4] = {w2.x, w2.y, w2.z, w2.w};
            float wa3[4] = {w3.x, w3.y, w3.z, w3.w};
#pragma unroll
            for (int h = 0; h < 4; ++h)
#pragma unroll
                for (int k = 0; k < 4; ++k)
                    acc[h][k] += wa0[h]*x0[k] + wa1[h]*x1[k]
                               + wa2[h]*x2[k] + wa3[h]*x3[k];
        }
        for (; j < cnt2; ++j) {
            int s0 = sh_s[j];
            float4 w0 = sh_w[j];
            ushort4 v0 = *(const ushort4*)(xb + (size_t)s0*IN_CH + c0);
            float x0[4] = {bf2f(v0.x), bf2f(v0.y), bf2f(v0.z), bf2f(v0.w)};
            float wa[4] = {w0.x, w0.y, w0.z, w0.w};
#pragma unroll
            for (int h = 0; h < 4; ++h)
#pragma unroll
                for (int k = 0; k < 4; ++k)
                    acc[h][k] += wa[h]*x0[k];
        }
        __syncthreads();
    }

    u16* op = aggx + (size_t)n * 1024;
#pragma unroll
    for (int h = 0; h < 4; ++h) {
        ushort4 o;
        o.x = f2bf(acc[h][0]); o.y = f2bf(acc[h][1]);
        o.z = f2bf(acc[h][2]); o.w = f2bf(acc[h][3]);
        *(ushort4*)(op + h*256 + c0) = o;
    }
}

// ---------------- per-dst softmax + weighted aggregation (layer 2) ----------
template<int H, int C, int VW, bool PRELU, int OUTMODE>
__global__ __launch_bounds__(64) void aggregate_k(
    const u16* __restrict__ hb,
    const float* __restrict__ als,
    const float* __restrict__ ald,
    const int* __restrict__ offs,
    const int* __restrict__ ssrc,
    const float* __restrict__ bias,
    const float* __restrict__ prelu_w,
    void* __restrict__ outv,
    const int* __restrict__ flag)
{
    constexpr int CT = H * C;
    constexpr int T  = 64;
    static_assert(CT == T * VW, "geometry");
    const int n   = blockIdx.x;
    const int tid = threadIdx.x;
    const int beg = offs[n], end = offs[n+1];

    float aldh[H];
#pragma unroll
    for (int h = 0; h < H; ++h) aldh[h] = ald[(size_t)n*H + h];

    float lsum[H];
#pragma unroll
    for (int h = 0; h < H; ++h) lsum[h] = 0.f;
    for (int e = beg + tid; e < end; e += T) {
        int s = ssrc[e];
#pragma unroll
        for (int h = 0; h < H; ++h) {
            float l = als[(size_t)s*H + h] + aldh[h];
            l = (l >= 0.f) ? l : 0.2f*l;
            lsum[h] += __expf(l);
        }
    }
#pragma unroll
    for (int h = 0; h < H; ++h) {
#pragma unroll
        for (int o = 32; o > 0; o >>= 1) lsum[h] += __shfl_xor(lsum[h], o);
    }
    float inv[H];
#pragma unroll
    for (int h = 0; h < H; ++h) inv[h] = 1.0f / lsum[h];

    __shared__ int   sh_s[T];
    __shared__ float sh_w[H][T];
    const int hh = (VW * tid) / C;
    float acc[VW];
#pragma unroll
    for (int k = 0; k < VW; ++k) acc[k] = 0.f;

    for (int chunk = beg; chunk < end; chunk += T) {
        int e = chunk + tid;
        if (e < end) {
            int s = ssrc[e];
            sh_s[tid] = s;
#pragma unroll
            for (int h = 0; h < H; ++h) {
                float l = als[(size_t)s*H + h] + aldh[h];
                l = (l >= 0.f) ? l : 0.2f*l;
                sh_w[h][tid] = __expf(l) * inv[h];
            }
        }
        __syncthreads();
        int cnt2 = min(T, end - chunk);
        int j = 0;
        for (; j + 4 <= cnt2; j += 4) {
            int   s0 = sh_s[j+0], s1 = sh_s[j+1], s2 = sh_s[j+2], s3 = sh_s[j+3];
            float w0 = sh_w[hh][j+0], w1 = sh_w[hh][j+1];
            float w2 = sh_w[hh][j+2], w3 = sh_w[hh][j+3];
            if constexpr (VW == 8) {
                u16x8 v0 = *(const u16x8*)(hb + (size_t)s0*CT + VW*tid);
                u16x8 v1 = *(const u16x8*)(hb + (size_t)s1*CT + VW*tid);
                u16x8 v2 = *(const u16x8*)(hb + (size_t)s2*CT + VW*tid);
                u16x8 v3 = *(const u16x8*)(hb + (size_t)s3*CT + VW*tid);
#pragma unroll
                for (int k = 0; k < 8; ++k) {
                    acc[k] += w0*bf2f(v0[k]) + w1*bf2f(v1[k])
                            + w2*bf2f(v2[k]) + w3*bf2f(v3[k]);
                }
            } else {
                ushort4 v0 = *(const ushort4*)(hb + (size_t)s0*CT + VW*tid);
                ushort4 v1 = *(const ushort4*)(hb + (size_t)s1*CT + VW*tid);
                ushort4 v2 = *(const ushort4*)(hb + (size_t)s2*CT + VW*tid);
                ushort4 v3 = *(const ushort4*)(hb + (size_t)s3*CT + VW*tid);
                acc[0] += w0*bf2f(v0.x) + w1*bf2f(v1.x) + w2*bf2f(v2.x) + w3*bf2f(v3.x);
                acc[1] += w0*bf2f(v0.y) + w1*bf2f(v1.y) + w2*bf2f(v2.y) + w3*bf2f(v3.y);
                acc[2] += w0*bf2f(v0.z) + w1*bf2f(v1.z) + w2*bf2f(v2.z) + w3*bf2f(v3.z);
                acc[3] += w0*bf2f(v0.w) + w1*bf2f(v1.w) + w2*bf2f(v2.w) + w3*bf2f(v3.w);
            }
        }
        for (; j < cnt2; ++j) {
            int s0 = sh_s[j];
            float w0 = sh_w[hh][j];
            if constexpr (VW == 8) {
                u16x8 v0 = *(const u16x8*)(hb + (size_t)s0*CT + VW*tid);
#pragma unroll
                for (int k = 0; k < 8; ++k) acc[k] += w0*bf2f(v0[k]);
            } else {
                ushort4 v0 = *(const ushort4*)(hb + (size_t)s0*CT + VW*tid);
                acc[0] += w0*bf2f(v0.x); acc[1] += w0*bf2f(v0.y);
                acc[2] += w0*bf2f(v0.z); acc[3] += w0*bf2f(v0.w);
            }
        }
        __syncthreads();
    }

#pragma unroll
    for (int k = 0; k < VW; ++k) acc[k] += bias[VW*tid + k];
    if (PRELU) {
        float pw = *prelu_w;
#pragma unroll
        for (int k = 0; k < VW; ++k) acc[k] = (acc[k] >= 0.f) ? acc[k] : pw*acc[k];
    }
    size_t ofs = (size_t)n*CT + VW*tid;
    bool bf = (OUTMODE == 1) || (OUTMODE == 2 && *flag);
    if (bf) {
        if constexpr (VW == 8) {
            u16x8 o;
#pragma unroll
            for (int k = 0; k < 8; ++k) o[k] = f2bf(acc[k]);
            *(u16x8*)((u16*)outv + ofs) = o;
        } else {
            ushort4 o; o.x=f2bf(acc[0]); o.y=f2bf(acc[1]); o.z=f2bf(acc[2]); o.w=f2bf(acc[3]);
            *(ushort4*)((u16*)outv + ofs) = o;
        }
    } else {
        float* op = (float*)outv + ofs;
#pragma unroll
        for (int k = 0; k < VW; k += 4)
            *(float4*)(op + k) = make_float4(acc[k], acc[k+1], acc[k+2], acc[k+3]);
    }
}

// ---------------------------------------------------------------------------
extern "C" void kernel_launch(void* const* d_in, const int* in_sizes, int n_in,
                              void* d_out, int out_size, void* d_ws, size_t ws_size,
                              hipStream_t stream)
{
    const void* x   = d_in[0];
    const int*  ei  = (const int*)d_in[1];
    const void* W1  = d_in[2];
    const void* as1 = d_in[3];
    const void* ad1 = d_in[4];
    const void* b1  = d_in[5];
    const void* pw  = d_in[6];
    const void* W2  = d_in[7];
    const void* as2 = d_in[8];
    const void* ad2 = d_in[9];
    const void* b2  = d_in[10];

    float* ws = (float*)d_ws;
    int*   flag = (int*)ws;                               // 16 slots
    float* as1f = ws + 16;                                // 512
    float* ad1f = as1f + 512;                             // 512
    float* b1f  = ad1f + 512;                             // 512
    float* as2f = b1f  + 512;                             // 256
    float* ad2f = as2f + 256;                             // 256
    float* b2f  = ad2f + 256;                             // 256
    float* pwf  = b2f  + 256;                             // 16
    float* vsd  = pwf + 16;                               // 2048 (8x256)
    u16*   W1t  = (u16*)(vsd + 2048);                     // 131072 u16
    u16*   W2t  = W1t + IN_CH*HEADS*HID;                  // 131072 u16
    float* als1 = (float*)(W2t + HEADS*HID*OUT_CH);       // 120000
    float* ald1 = als1 + (size_t)N_NODES*HEADS;           // 120000
    // zero region: als2v, ald2v, cnt contiguous (90000 ints)
    float* als2v = ald1 + (size_t)N_NODES*HEADS;          // 30000
    float* ald2v = als2v + N_NODES;                       // 30000
    int*   cnt    = (int*)(ald2v + N_NODES);              // 30000
    int*   offs   = cnt + N_NODES;                        // 30004 (pad)
    int*   cursor = offs + 30004;                         // 30000
    int*   btot   = cursor + N_NODES;                     // 32
    int*   bpref  = btot + 32;                            // 36 (unused, kept for layout)
    int*   ssrc   = bpref + 36;                           // 510004
    u16*   xb     = (u16*)(ssrc + 510004);                // 30000*256 u16
    u16*   aggx   = xb + (size_t)N_NODES*IN_CH;           // 30000*1024 u16
    u16*   h1pb   = aggx + (size_t)N_NODES*1024;          // 30000*512 u16
    u16*   h2b    = aggx;  // alias: aggx dead after gemm_h1

    const int NB = (N_NODES + 1023) / 1024;   // 30 scan blocks
    const int CB = (TOT_E + 255) / 256;       // 1993 count blocks

    // dtype detect, consolidated conversion/zero, then coalesced vsd
    detect_k<<<1, 256, 0, stream>>>((const unsigned int*)x, flag);
    wconv_k<<<1386, 256, 0, stream>>>(W1, W2, as1, ad1, b1, as2, ad2, b2, pw,
                                      W1t, W2t, as1f, ad1f, b1f, as2f, ad2f, b2f, pwf,
                                      (int*)als2v, flag);
    prep_av_k<<<8, 256, 0, stream>>>(W1t, as1f, ad1f, vsd);

    // fused x-convert + layer-1 logits + CSR count
    xprep_k<<<XPB + CB, 256, 0, stream>>>(x, vsd, xb, als1, ald1, ei, cnt, flag);

    // CSR scan (scan2 folded into scan3) + scatter
    scan1_k  <<<NB, 1024, 0, stream>>>(cnt, offs, btot);
    scan3_k  <<<NB, 1024, 0, stream>>>(cnt, offs, cursor, btot, NB);
    scatter_k<<<CB, 256, 0, stream>>>(ei, cursor, ssrc);

    // ---- layer 1 (aggregate-first) ----
    aggx_k<<<N_NODES, 64, 0, stream>>>(xb, als1, ald1, offs, ssrc, aggx);
    dim3 gh1(1, (N_NODES+127)/128, HEADS);
    gemm_h1_k<<<gh1, 256, 0, stream>>>(aggx, W1t, h1pb, b1f, pwf, N_NODES);

    // ---- layer 2 ----
    dim3 g2(256/128, (N_NODES+127)/128);
    gemm_bf_k<<<g2, 256, 0, stream>>>(h1pb, W2t, h2b, as2f, ad2f, als2v, ald2v,
                                      N_NODES, OUT_CH, HEADS*HID, 1, 8);
    aggregate_k<1, OUT_CH, 4, false, 2>
        <<<N_NODES, 64, 0, stream>>>(h2b, als2v, ald2v, offs, ssrc, b2f, nullptr, d_out, flag);
}